// Round 1
// 1110.531 us; speedup vs baseline: 1.0522x; 1.0522x over previous
//
#include <hip/hip_runtime.h>

#define NA 8192
#define NB 8192
#define N_LAYERS 16

typedef _Float16 half_t;
typedef _Float16 half8_t __attribute__((ext_vector_type(8)));
typedef float float4_t __attribute__((ext_vector_type(4)));

// Raw barrier that does NOT drain vmcnt: LDS-visibility only. Keeps the
// global prefetch for the next row-group in flight across the reduction.
__device__ __forceinline__ void barrier_lds() {
    asm volatile("s_waitcnt lgkmcnt(0)" ::: "memory");
    __builtin_amdgcn_s_barrier();
    asm volatile("" ::: "memory");
}

// ---------------------------------------------------------------------------
// Fused per-layer kernel: block = one row-chunk (n_groups*2 rows).
//   pass (per 2-row group, pipelined):
//     e regs <- E[2 rows] (or exp(-C/eps))     [prefetched one group ahead]
//     rs0/rs1 = row dots with v (v register-resident, loaded once)
//     shfl+LDS reduce -> u0,u1   (raw s_barrier, vmcnt stays in flight)
//     acc[cols] += u0*e0 + u1*e1               [E reused from VGPRs: 1 global
//                                               pass per layer instead of 2]
//   epilogue: partial[rc][cols] = acc
// ---------------------------------------------------------------------------
template <bool READ_C, bool WRITE_E, bool HAS_V>
__global__ __launch_bounds__(256, 2) void sink_fused(
    const float* __restrict__ C, const half_t* __restrict__ Ein,
    half_t* __restrict__ Eout, const float* __restrict__ v,
    const float* __restrict__ alpha, const float* __restrict__ d_eps,
    float* __restrict__ u, float* __restrict__ partial, int n_groups)
{
    const int t = threadIdx.x;
    const int rc = blockIdx.x;
    const int row0 = rc * (n_groups * 2);
    __shared__ float sred[2][8];   // [parity][wave*2 + row]

    // v weights for this thread's 32 columns (4 half8 groups): loaded ONCE.
    float4_t w0[4], w1[4];
    if constexpr (HAS_V) {
        const float4_t* vv = (const float4_t*)v;
#pragma unroll
        for (int k = 0; k < 4; ++k) {
            const int g = k * 256 + t;
            w0[k] = vv[2 * g];
            w1[k] = vv[2 * g + 1];
        }
    }

    float acc[4][8];
#pragma unroll
    for (int k = 0; k < 4; ++k)
#pragma unroll
        for (int j = 0; j < 8; ++j) acc[k][j] = 0.0f;

    // block reduction: 64-lane shfl tree + 4-wave LDS exchange (parity slot).
    auto usum = [&](float rs0, float rs1, int par) -> float2 {
#pragma unroll
        for (int m = 1; m < 64; m <<= 1) {
            rs0 += __shfl_xor(rs0, m, 64);
            rs1 += __shfl_xor(rs1, m, 64);
        }
        const int lane = t & 63, wid = t >> 6;
        if (lane == 0) { sred[par][wid * 2] = rs0; sred[par][wid * 2 + 1] = rs1; }
        barrier_lds();
        const float S0 = (sred[par][0] + sred[par][2]) + (sred[par][4] + sred[par][6]);
        const float S1 = (sred[par][1] + sred[par][3]) + (sred[par][5] + sred[par][7]);
        return make_float2(S0, S1);
    };

    if constexpr (!READ_C) {
        // ------------------ steady path: read fp16 E ------------------
        const half8_t* Eb = (const half8_t*)Ein;
        half8_t bufA[2][4], bufB[2][4];

        auto load = [&](half8_t (&d)[2][4], int r0) {
#pragma unroll
            for (int rr = 0; rr < 2; ++rr)
#pragma unroll
                for (int k = 0; k < 4; ++k)
                    d[rr][k] = Eb[(size_t)(r0 + rr) * (NB / 8) + k * 256 + t];
        };

        auto step = [&](half8_t (&cur)[2][4], half8_t (&nxt)[2][4], int r0,
                        int par, bool pf) {
            if (pf) load(nxt, r0 + 2);                 // issued BEFORE barrier
            const float a0 = alpha[r0], a1 = alpha[r0 + 1];
            float rs0 = 0.0f, rs1 = 0.0f;
#pragma unroll
            for (int k = 0; k < 4; ++k) {
                rs0 += (float)cur[0][k][0] * w0[k].x + (float)cur[0][k][1] * w0[k].y +
                       (float)cur[0][k][2] * w0[k].z + (float)cur[0][k][3] * w0[k].w +
                       (float)cur[0][k][4] * w1[k].x + (float)cur[0][k][5] * w1[k].y +
                       (float)cur[0][k][6] * w1[k].z + (float)cur[0][k][7] * w1[k].w;
                rs1 += (float)cur[1][k][0] * w0[k].x + (float)cur[1][k][1] * w0[k].y +
                       (float)cur[1][k][2] * w0[k].z + (float)cur[1][k][3] * w0[k].w +
                       (float)cur[1][k][4] * w1[k].x + (float)cur[1][k][5] * w1[k].y +
                       (float)cur[1][k][6] * w1[k].z + (float)cur[1][k][7] * w1[k].w;
            }
            const float2 S = usum(rs0, rs1, par);
            const float u0 = a0 / S.x, u1 = a1 / S.y;
            if (t == 0) { u[r0] = u0; u[r0 + 1] = u1; }
#pragma unroll
            for (int k = 0; k < 4; ++k)
#pragma unroll
                for (int j = 0; j < 8; ++j)
                    acc[k][j] += u0 * (float)cur[0][k][j] + u1 * (float)cur[1][k][j];
        };

        load(bufA, row0);
        for (int s = 0; s < n_groups; s += 2) {        // n_groups is even
            step(bufA, bufB, row0 + 2 * s, 0, true);
            step(bufB, bufA, row0 + 2 * (s + 1), 1, s + 2 < n_groups);
        }
    } else {
        // ------- layer-0 / no-E path: read fp32 C, exp, (store E) -------
        const float inv_eps = 1.0f / d_eps[0];
        const float4_t* Cb = (const float4_t*)C;
        float4_t bufA[2][8], bufB[2][8];

        auto load = [&](float4_t (&d)[2][8], int r0) {
#pragma unroll
            for (int rr = 0; rr < 2; ++rr)
#pragma unroll
                for (int k = 0; k < 4; ++k) {
                    const int g = k * 256 + t;
                    d[rr][2 * k]     = Cb[(size_t)(r0 + rr) * (NB / 4) + 2 * g];
                    d[rr][2 * k + 1] = Cb[(size_t)(r0 + rr) * (NB / 4) + 2 * g + 1];
                }
        };

        auto step = [&](float4_t (&cur)[2][8], float4_t (&nxt)[2][8], int r0,
                        int par, bool pf) {
            if (pf) load(nxt, r0 + 2);
            const float a0 = alpha[r0], a1 = alpha[r0 + 1];
            half8_t h[2][4];                       // retained for accumulate
            float rs0 = 0.0f, rs1 = 0.0f;
#pragma unroll
            for (int rr = 0; rr < 2; ++rr) {
                float rs = 0.0f;
#pragma unroll
                for (int k = 0; k < 4; ++k) {
                    const float4_t c0 = cur[rr][2 * k], c1 = cur[rr][2 * k + 1];
                    const float e0 = __expf(-c0.x * inv_eps);
                    const float e1 = __expf(-c0.y * inv_eps);
                    const float e2 = __expf(-c0.z * inv_eps);
                    const float e3 = __expf(-c0.w * inv_eps);
                    const float e4 = __expf(-c1.x * inv_eps);
                    const float e5 = __expf(-c1.y * inv_eps);
                    const float e6 = __expf(-c1.z * inv_eps);
                    const float e7 = __expf(-c1.w * inv_eps);
                    h[rr][k][0] = (_Float16)e0; h[rr][k][1] = (_Float16)e1;
                    h[rr][k][2] = (_Float16)e2; h[rr][k][3] = (_Float16)e3;
                    h[rr][k][4] = (_Float16)e4; h[rr][k][5] = (_Float16)e5;
                    h[rr][k][6] = (_Float16)e6; h[rr][k][7] = (_Float16)e7;
                    if constexpr (HAS_V) {
                        rs += e0 * w0[k].x + e1 * w0[k].y + e2 * w0[k].z + e3 * w0[k].w +
                              e4 * w1[k].x + e5 * w1[k].y + e6 * w1[k].z + e7 * w1[k].w;
                    } else {
                        rs += ((e0 + e1) + (e2 + e3)) + ((e4 + e5) + (e6 + e7));
                    }
                }
                if (rr == 0) rs0 = rs; else rs1 = rs;
            }
            if constexpr (WRITE_E) {
#pragma unroll
                for (int rr = 0; rr < 2; ++rr)
#pragma unroll
                    for (int k = 0; k < 4; ++k)
                        ((half8_t*)Eout)[(size_t)(r0 + rr) * (NB / 8) + k * 256 + t] = h[rr][k];
            }
            const float2 S = usum(rs0, rs1, par);
            const float u0 = a0 / S.x, u1 = a1 / S.y;
            if (t == 0) { u[r0] = u0; u[r0 + 1] = u1; }
#pragma unroll
            for (int k = 0; k < 4; ++k)
#pragma unroll
                for (int j = 0; j < 8; ++j)
                    acc[k][j] += u0 * (float)h[0][k][j] + u1 * (float)h[1][k][j];
        };

        load(bufA, row0);
        for (int s = 0; s < n_groups; s += 2) {
            step(bufA, bufB, row0 + 2 * s, 0, true);
            step(bufB, bufA, row0 + 2 * (s + 1), 1, s + 2 < n_groups);
        }
    }

    // partial[rc][cols] = column accumulators (coalesced float4 stores)
#pragma unroll
    for (int k = 0; k < 4; ++k) {
        float4_t o0 = {acc[k][0], acc[k][1], acc[k][2], acc[k][3]};
        float4_t o1 = {acc[k][4], acc[k][5], acc[k][6], acc[k][7]};
        float4_t* p = (float4_t*)(partial + (size_t)rc * NB + (size_t)(k * 256 + t) * 8);
        p[0] = o0;
        p[1] = o1;
    }
}

// ---------------------------------------------------------------------------
// v[j] = beta[j] / sum_rc partial[rc][j].  Block = 32 cols x 8 rc-slices.
// ---------------------------------------------------------------------------
__global__ __launch_bounds__(256) void sink_v_combine(
    const float* __restrict__ partial, const float* __restrict__ beta,
    float* __restrict__ v, int nvc)
{
    const int c = blockIdx.x * 32 + (threadIdx.x & 31);
    const int sl = threadIdx.x >> 5;
    float s = 0.0f;
#pragma unroll 4
    for (int i = sl; i < nvc; i += 8) s += partial[(size_t)i * NB + c];
    __shared__ float sm[8][32];
    sm[sl][threadIdx.x & 31] = s;
    __syncthreads();
    if (threadIdx.x < 32) {
        float tot = 0.0f;
#pragma unroll
        for (int k = 0; k < 8; ++k) tot += sm[k][threadIdx.x];
        v[c] = beta[c] / tot;
    }
}

// ---------------------------------------------------------------------------
// f = eps*log(u), g = eps*log(v), concatenated into d_out.
// ---------------------------------------------------------------------------
__global__ __launch_bounds__(256) void sink_finalize(
    const float* __restrict__ u, const float* __restrict__ v,
    const float* __restrict__ d_eps, float* __restrict__ out)
{
    const int i = blockIdx.x * 256 + threadIdx.x;
    const float eps = d_eps[0];
    if (i < NA) {
        out[i] = eps * logf(u[i]);
    } else if (i < NA + NB) {
        out[i] = eps * logf(v[i - NA]);
    }
}

extern "C" void kernel_launch(void* const* d_in, const int* in_sizes, int n_in,
                              void* d_out, int out_size, void* d_ws, size_t ws_size,
                              hipStream_t stream)
{
    const float* alpha = (const float*)d_in[0];
    const float* beta  = (const float*)d_in[1];
    const float* C     = (const float*)d_in[2];
    const float* d_eps = (const float*)d_in[3];
    float* out = (float*)d_out;

    const size_t eBytes   = (size_t)NA * NB * sizeof(half_t);  // 128 MiB
    const size_t vecBytes = (size_t)NA * sizeof(float);        // 32 KiB

    // Pick largest row-chunk count (parallelism) that fits the workspace.
    int nvc = 0;
    bool useE = false;
    if      (ws_size >= eBytes + (size_t)512 * NB * 4 + 2 * vecBytes) { useE = true; nvc = 512; }
    else if (ws_size >= eBytes + (size_t)256 * NB * 4 + 2 * vecBytes) { useE = true; nvc = 256; }
    else if (ws_size >= eBytes + (size_t)128 * NB * 4 + 2 * vecBytes) { useE = true; nvc = 128; }
    else if (ws_size >= (size_t)512 * NB * 4 + 2 * vecBytes)          { nvc = 512; }
    else if (ws_size >= (size_t)256 * NB * 4 + 2 * vecBytes)          { nvc = 256; }
    else                                                              { nvc = 128; }

    char* ws = (char*)d_ws;
    size_t off = 0;
    half_t* E = nullptr;
    if (useE) { E = (half_t*)ws; off += eBytes; }
    float* partial = (float*)(ws + off); off += (size_t)nvc * NB * sizeof(float);
    float* u = (float*)(ws + off); off += vecBytes;
    float* v = (float*)(ws + off);

    const int ng = (NA / nvc) / 2;      // 2-row groups per block (even: 8/16/32)
    const dim3 blk(256);
    const dim3 gridF(nvc);
    const dim3 gridC(NB / 32);
    const dim3 gridFin((NA + NB) / 256);

    for (int layer = 0; layer < N_LAYERS; ++layer) {
        if (layer == 0) {
            if (useE)
                sink_fused<true, true, false><<<gridF, blk, 0, stream>>>(
                    C, nullptr, E, nullptr, alpha, d_eps, u, partial, ng);
            else
                sink_fused<true, false, false><<<gridF, blk, 0, stream>>>(
                    C, nullptr, nullptr, nullptr, alpha, d_eps, u, partial, ng);
        } else {
            if (useE)
                sink_fused<false, false, true><<<gridF, blk, 0, stream>>>(
                    nullptr, E, nullptr, v, alpha, d_eps, u, partial, ng);
            else
                sink_fused<true, false, true><<<gridF, blk, 0, stream>>>(
                    C, nullptr, nullptr, v, alpha, d_eps, u, partial, ng);
        }
        sink_v_combine<<<gridC, blk, 0, stream>>>(partial, beta, v, nvc);
    }
    sink_finalize<<<gridFin, blk, 0, stream>>>(u, v, d_eps, out);
}